// Round 1
// 264.776 us; speedup vs baseline: 1.0439x; 1.0439x over previous
//
#include <hip/hip_runtime.h>

#define BATCH 8
#define SEQ   65536
#define CH    64
#define FILT  64
#define DLAT  256

typedef __bf16 bfrag  __attribute__((ext_vector_type(8)));
typedef float  floatx4 __attribute__((ext_vector_type(4)));

// ------------- prep: s, d, and folded kernel kmod[b][k][f][c] (bf16) -------
// kmod[b][k][f][c] = ker[k][c][f] * s[b][c] * d[b][f]
__global__ __launch_bounds__(256) void prep_kernel(
    const float* __restrict__ ltnt, const float* __restrict__ ker,
    const float* __restrict__ Wd,   const float* __restrict__ bd,
    __bf16* __restrict__ kmod)
{
    int b = blockIdx.x, tid = threadIdx.x;
    __shared__ float red[4][64];
    __shared__ float s_sh[64];
    __shared__ float d_sh[64];
    int f = tid & 63, p = tid >> 6;

    // s = softplus(ltnt @ Wd + bd) + 1
    float sum = 0.f;
    #pragma unroll 8
    for (int j = p * 64; j < p * 64 + 64; ++j)
        sum += ltnt[b * DLAT + j] * Wd[j * FILT + f];
    red[p][f] = sum;
    __syncthreads();
    if (tid < 64) {
        float tot = red[0][tid] + red[1][tid] + red[2][tid] + red[3][tid] + bd[tid];
        float sp = (tot > 20.f) ? tot : log1pf(expf(tot));
        s_sh[tid] = sp + 1.f;
    }
    __syncthreads();

    // d[f] = rsqrt( sum_{k,c} (ker[k,c,f]*s[c])^2 + eps )   (f32, matches ref)
    float s2 = 0.f;
    for (int k = 0; k < 3; ++k)
        #pragma unroll
        for (int c = p * 16; c < p * 16 + 16; ++c) {
            float w = ker[k * 4096 + c * 64 + f];
            float sc = s_sh[c];
            s2 += w * w * sc * sc;
        }
    __syncthreads();
    red[p][f] = s2;
    __syncthreads();
    if (tid < 64) {
        float tot = red[0][tid] + red[1][tid] + red[2][tid] + red[3][tid];
        d_sh[tid] = rsqrtf(tot + 1e-8f);
    }
    __syncthreads();

    // folded kernel, bf16, layout [k][f][c] contiguous in c
    for (int o = tid; o < 3 * 64 * 64; o += 256) {
        int k = o >> 12, ff = (o >> 6) & 63, c = o & 63;
        kmod[b * 12288 + o] = (__bf16)(ker[k * 4096 + c * 64 + ff] * s_sh[c] * d_sh[ff]);
    }
}

// ---------------------------- conv --------------------------------
struct RawA { float4 v[3][2][2]; };   // [tap k][chh][lo/hi float4]

__device__ __forceinline__ float4 scale4(float4 v, float s) {
    v.x *= s; v.y *= s; v.z *= s; v.w *= s; return v;
}

__device__ __forceinline__ RawA loadA(const float* __restrict__ xb,
                                      int r0, int m, int q) {
    RawA r;
    if (r0 >= 1 && r0 <= SEQ - 17) {            // interior fast path (uniform)
        const float* p = xb + (size_t)(r0 + m - 1) * CH + q * 8;
        #pragma unroll
        for (int k = 0; k < 3; ++k)
            #pragma unroll
            for (int h = 0; h < 2; ++h) {
                r.v[k][h][0] = *(const float4*)(p + k * CH + h * 32);
                r.v[k][h][1] = *(const float4*)(p + k * CH + h * 32 + 4);
            }
    } else {                                    // batch-edge tiles only
        #pragma unroll
        for (int k = 0; k < 3; ++k) {
            int g = r0 + m - 1 + k;
            bool ok = (unsigned)g < (unsigned)SEQ;
            const float* p = xb + (size_t)(ok ? g : 0) * CH + q * 8;
            float sc = ok ? 1.f : 0.f;
            #pragma unroll
            for (int h = 0; h < 2; ++h) {
                r.v[k][h][0] = scale4(*(const float4*)(p + h * 32), sc);
                r.v[k][h][1] = scale4(*(const float4*)(p + h * 32 + 4), sc);
            }
        }
    }
    return r;
}

__device__ __forceinline__ bfrag cvt8(float4 a, float4 b) {
    bfrag r;
    r[0] = (__bf16)a.x; r[1] = (__bf16)a.y; r[2] = (__bf16)a.z; r[3] = (__bf16)a.w;
    r[4] = (__bf16)b.x; r[5] = (__bf16)b.y; r[6] = (__bf16)b.z; r[7] = (__bf16)b.w;
    return r;
}

__global__ __launch_bounds__(256, 2) void conv_kernel(
    const float* __restrict__ data, const __bf16* __restrict__ kmod,
    float* __restrict__ out)
{
    // wave-private staging tile: 16 rows x 64 cols f32, XOR-swizzled.
    // swizzle: scol = col ^ ((((row&3) ^ (row>>2)) & 3) << 4)
    //  - acc writes (nt,r fixed; q varies): bank bit4 toggles with q -> 2-way max (free)
    //  - f4 reads  (i fixed; q,m vary):    uniform 8 slots/bank (b128 minimum)
    __shared__ float lds[4][16][64];   // 16 KiB / block

    int tid  = threadIdx.x;
    int b    = blockIdx.x >> 6;        // 64 blocks per batch
    int blk  = blockIdx.x & 63;        // 1024 rows per block
    int wave = tid >> 6, lane = tid & 63;
    int m = lane & 15, q = lane >> 4;

    // B fragments (folded kernel) -> registers, once. 24 frags = 96 VGPRs.
    const __bf16* kb = kmod + b * 12288;
    bfrag Bf[4][3][2];
    #pragma unroll
    for (int nt = 0; nt < 4; ++nt)
        #pragma unroll
        for (int k = 0; k < 3; ++k)
            #pragma unroll
            for (int h = 0; h < 2; ++h)
                Bf[nt][k][h] = *(const bfrag*)(kb + (k * 64 + nt * 16 + m) * 64 + h * 32 + q * 8);

    const float* xb = data + (size_t)b * SEQ * CH;
    float*       ob = out  + (size_t)b * SEQ * FILT;
    float*       lw = &lds[wave][0][0];

    // wave-interleaved 16-row tiles: r0 = blk*1024 + wave*16 + t*64
    int base = blk * 1024 + wave * 16;

    RawA raw = loadA(xb, base, m, q);
    bfrag Af[3][2];
    #pragma unroll
    for (int k = 0; k < 3; ++k)
        #pragma unroll
        for (int h = 0; h < 2; ++h)
            Af[k][h] = cvt8(raw.v[k][h][0], raw.v[k][h][1]);

    #pragma unroll 1
    for (int t = 0; t < 16; ++t) {
        int r0 = base + t * 64;

        if (t < 15)                     // issue next tile's loads (prefetch)
            raw = loadA(xb, r0 + 64, m, q);

        floatx4 acc[4] = {floatx4{0,0,0,0}, floatx4{0,0,0,0},
                          floatx4{0,0,0,0}, floatx4{0,0,0,0}};
        #pragma unroll
        for (int nt = 0; nt < 4; ++nt)
            #pragma unroll
            for (int k = 0; k < 3; ++k)
                #pragma unroll
                for (int h = 0; h < 2; ++h)
                    acc[nt] = __builtin_amdgcn_mfma_f32_16x16x32_bf16(
                        Af[k][h], Bf[nt][k][h], acc[nt], 0, 0, 0);

        // --- stage accumulator tile through wave-private LDS (swizzled) ---
        // acc[nt][r] = out[row = q*4+r][col = nt*16+m]
        #pragma unroll
        for (int nt = 0; nt < 4; ++nt)
            #pragma unroll
            for (int r = 0; r < 4; ++r) {
                int row = q * 4 + r;                       // row&3 == r, row>>2 == q
                int sc  = (nt * 16 + m) ^ ((((r ^ q) & 3)) << 4);
                lw[row * 64 + sc] = acc[nt][r];
            }

        // --- read back contiguous float4 and store fully coalesced ---
        // instruction i: rows i*4+q, cols 4m..4m+3 -> wave writes 1 KiB contiguous
        float* op = ob + (size_t)r0 * FILT;
        #pragma unroll
        for (int i = 0; i < 4; ++i) {
            int row = i * 4 + q;                           // row&3 == q, row>>2 == i
            int sc  = (m * 4) ^ ((((q ^ i) & 3)) << 4);
            floatx4 v = *(const floatx4*)(lw + row * 64 + sc);
            __builtin_nontemporal_store(v,
                (floatx4*)(op + (size_t)row * FILT + m * 4));
        }

        if (t < 15) {                   // convert prefetched tile (waits here,
            #pragma unroll              //  after MFMAs+stores, not before)
            for (int k = 0; k < 3; ++k)
                #pragma unroll
                for (int h = 0; h < 2; ++h)
                    Af[k][h] = cvt8(raw.v[k][h][0], raw.v[k][h][1]);
        }
    }
}

// ---------------------------------------------------------------------------
extern "C" void kernel_launch(void* const* d_in, const int* in_sizes, int n_in,
                              void* d_out, int out_size, void* d_ws, size_t ws_size,
                              hipStream_t stream) {
    const float* data = (const float*)d_in[0];
    const float* ltnt = (const float*)d_in[1];
    const float* ker  = (const float*)d_in[2];
    const float* Wd   = (const float*)d_in[3];
    const float* bd   = (const float*)d_in[4];
    float* out = (float*)d_out;

    __bf16* kmod = (__bf16*)d_ws;     // 8 * 12288 bf16 = 192 KiB

    prep_kernel<<<BATCH, 256, 0, stream>>>(ltnt, ker, Wd, bd, kmod);
    conv_kernel<<<BATCH * 64, 256, 0, stream>>>(data, kmod, out);
}